// Round 18
// baseline (585.565 us; speedup 1.0000x reference)
//
#include <hip/hip_runtime.h>
#include <stdint.h>

typedef __attribute__((ext_vector_type(8))) short bf16x8;
typedef __attribute__((ext_vector_type(4))) float f32x4;

__device__ __forceinline__ unsigned short f2bf(float f) {
  unsigned u = __float_as_uint(f);
  u += 0x7FFFu + ((u >> 16) & 1u);
  return (unsigned short)(u >> 16);
}
__device__ __forceinline__ float bf2f(unsigned short b) {
  return __uint_as_float(((unsigned)b) << 16);
}
// monotone float->u32 transform (order-preserving), and inverse
__device__ __forceinline__ unsigned xform(float s) {
  unsigned u = __float_as_uint(s);
  return (u & 0x80000000u) ? ~u : (u | 0x80000000u);
}
__device__ __forceinline__ float inv_xform(unsigned t) {
  unsigned u = (t & 0x80000000u) ? (t & 0x7FFFFFFFu) : ~t;
  return __uint_as_float(u);
}

__device__ __forceinline__ void gl_lds16(const void* g, void* l) {
  __builtin_amdgcn_global_load_lds(
      (const __attribute__((address_space(1))) unsigned*)g,
      (__attribute__((address_space(3))) unsigned*)l, 16, 0, 0);
}

// ---- both mems fp32 -> bf16 into concat buffer [2048,512] + zero scratch ----
__global__ void kcvt2z(const float* __restrict__ memR, const float* __restrict__ memF,
                       unsigned short* __restrict__ memB, uint4* __restrict__ zbuf,
                       int nz4) {
  int i = blockIdx.x * 256 + threadIdx.x;  // 0..1048575
  const float* src = (i < 524288) ? memR : memF;
  memB[i] = f2bf(src[i & 524287]);
  if (i < nz4) zbuf[i] = make_uint4(0u, 0u, 0u, 0u);
}

// ------- fused: per-pixel l2norm + q fp32 out (both regions) + qf bf16 -------
__global__ __launch_bounds__(256) void kqf2(const float* __restrict__ feat,
                                            unsigned* __restrict__ qf32,
                                            float* __restrict__ out) {
  __shared__ unsigned buf[32 * 256];  // 32 KiB
  __shared__ float red[4][64];
  int n0 = blockIdx.x * 64;
  int lane = threadIdx.x & 63, wv = threadIdx.x >> 6;
  int b = n0 >> 12, hw0 = n0 & 4095;
  const float* fp = feat + (size_t)b * (512 * 4096) + (size_t)(wv * 128) * 4096 + hw0 + lane;
  unsigned pk[64];
  float ss = 0.f;
  #pragma unroll
  for (int i = 0; i < 64; ++i) {
    float v0 = fp[(size_t)(2 * i) * 4096];
    float v1 = fp[(size_t)(2 * i + 1) * 4096];
    ss += v0 * v0 + v1 * v1;
    pk[i] = (unsigned)f2bf(v0) | ((unsigned)f2bf(v1) << 16);
  }
  red[wv][lane] = ss;
  __syncthreads();
  float tot = red[0][lane] + red[1][lane] + red[2][lane] + red[3][lane];
  float rn = 1.0f / fmaxf(sqrtf(tot), 1e-12f);
  float* ob = out + ((size_t)b * 2048 + wv * 128) * 4096 + hw0 + lane;
  #pragma unroll
  for (int i = 0; i < 64; ++i) {
    float q0 = bf2f((unsigned short)(pk[i] & 0xFFFFu)) * rn;
    float q1 = bf2f((unsigned short)(pk[i] >> 16)) * rn;
    ob[(size_t)(2 * i) * 4096] = q0;
    ob[(size_t)(2 * i) * 4096 + (size_t)1024 * 4096] = q0;
    ob[(size_t)(2 * i + 1) * 4096] = q1;
    ob[(size_t)(2 * i + 1) * 4096 + (size_t)1024 * 4096] = q1;
    pk[i] = (unsigned)f2bf(q0) | ((unsigned)f2bf(q1) << 16);
  }
  #pragma unroll
  for (int p = 0; p < 2; ++p) {
    __syncthreads();
    if ((lane >> 5) == p) {
      int px = lane & 31;
      #pragma unroll
      for (int i = 0; i < 64; ++i) buf[px * 256 + ((wv * 64 + i) ^ px)] = pk[i];
    }
    __syncthreads();
    #pragma unroll
    for (int r = 0; r < 32; ++r) {
      int row = p * 32 + r;
      qf32[(size_t)(n0 + row) * 256 + threadIdx.x] = buf[r * 256 + (threadIdx.x ^ r)];
    }
  }
}

// ---- merged GEMM (A[*,K] x B[*,K]^T), 128n x 256m tile, BK=32, ring-3 -------
// B-DIRECT variant: A staged via global_load_lds ring-3 (slots 8 KB, A-only);
// B fragments loaded straight from global (L2-hot 2 MB panel) into registers,
// double-buffered one K-step ahead.  LDS read traffic/step drops 3x (the
// measured bottleneck); B rides the L1/L2 path instead.
// Per iter t: ds_read A(t) [4x b128]; issue B(t+1) [8x dwordx4 -> regs];
//   issue STAGE_A(t+2) [2x gl_lds]; 32 MFMA with B(t) regs; vmcnt(2)
//   [A(t+1)+B(t+1) landed, A(t+2) in flight -- never 0 mid-loop]; barrier.
// MODE 0: score pass  -> rowPackAll (u64 max) + colMaxAll (u32 max); br = m0>>10
// MODE 1: read pass   -> E[n, 2048] = exp(score2) bf16 + rowsumAll atomics
// MODE 2: PV pass     -> out = (E_br @ muT)/rowsum, fp32 transposed store; br = m0>>9
template <int MODE, int LGX, int K>
__global__ __launch_bounds__(256, 2) void gemmW(
    const unsigned short* __restrict__ A, const unsigned short* __restrict__ B,
    int lda, int ldb,
    unsigned long long* __restrict__ rowPackAll, unsigned* __restrict__ colMaxAll,
    unsigned short* __restrict__ Eout, float* __restrict__ rowsumAll,
    float* __restrict__ out) {
  __shared__ __align__(16) unsigned short sm[36864];  // 72 KiB (ring uses 24 KiB)
  const int bid = blockIdx.x;
  const int xcd = bid & 7;
  const int tt0 = bid >> 3;
  const int m0 = (tt0 & ((1 << LGX) - 1)) * 256;
  const int n0 = (xcd + (tt0 >> LGX) * 8) * 128;
  const int tid = threadIdx.x;
  const int wid = tid >> 6, lane = tid & 63;
  const int wn = wid >> 1, wc = wid & 1;
  const int lr = lane & 15, lg = lane >> 4;
  // staging source chunk pre-swizzle (lane-constant):
  const int ssw = ((tid & 3) ^ ((tid >> 2) & 3) ^ ((tid >> 4) & 3)) * 8;
  // read-side swizzle (lane-constant, fragment-row-independent):
  const int rsw = (lg ^ (lr & 3) ^ ((lr >> 2) & 3)) * 8;
  const size_t brOffA = (MODE == 2) ? (size_t)((m0 >> 9) * 1024) : 0;
  constexpr int nt = K >> 5;
  // per-lane B base: row (m0 + wc*128 + lr), k-offset lg*8
  const unsigned short* Bp = B + (size_t)(m0 + wc * 128 + lr) * ldb + lg * 8;

  f32x4 acc[4][8];
  #pragma unroll
  for (int i = 0; i < 4; ++i)
    #pragma unroll
    for (int j = 0; j < 8; ++j) acc[i][j] = (f32x4){0.f, 0.f, 0.f, 0.f};

  bf16x8 breg[2][8];

  auto STAGE_A = [&](int slot, int t) {
    const int k0 = t << 5;
    #pragma unroll
    for (int i = 0; i < 2; ++i) {
      int row = i * 64 + (tid >> 2);
      gl_lds16(A + brOffA + (size_t)(n0 + row) * lda + k0 + ssw,
               sm + slot * 4096 + i * 2048 + wid * 512);
    }
  };
  auto LOADB = [&](int buf, int t) {
    const int k0 = t << 5;
    #pragma unroll
    for (int f = 0; f < 8; ++f)
      breg[buf][f] = *(const bf16x8*)&Bp[(size_t)(f * 16) * ldb + k0];
  };

  // prologue: B(0)->regs, A(0),A(1)->LDS in flight; drain B(0)+A(0)
  LOADB(0, 0);
  STAGE_A(0, 0);
  STAGE_A(1, 1);
  asm volatile("s_waitcnt vmcnt(2)" ::: "memory");
  __builtin_amdgcn_s_barrier();
  __builtin_amdgcn_sched_barrier(0);

  #pragma unroll
  for (int t = 0; t < nt; ++t) {
    const int slot = t % 3;
    const unsigned short* As = sm + slot * 4096;
    bf16x8 af[4];
    #pragma unroll
    for (int f = 0; f < 4; ++f)
      af[f] = *(const bf16x8*)&As[(wn * 64 + f * 16 + lr) * 32 + rsw];
    if (t + 1 < nt) LOADB((t + 1) & 1, t + 1);   // B for next step -> other buf
    if (t + 2 < nt) STAGE_A((t + 2) % 3, t + 2); // refill slot freed at t-1
    __builtin_amdgcn_s_setprio(1);
    #pragma unroll
    for (int fi = 0; fi < 4; ++fi)
      #pragma unroll
      for (int fj = 0; fj < 8; ++fj)
        acc[fi][fj] = __builtin_amdgcn_mfma_f32_16x16x32_bf16(af[fi], breg[t & 1][fj],
                                                              acc[fi][fj], 0, 0, 0);
    __builtin_amdgcn_s_setprio(0);
    if (t + 2 < nt) {
      asm volatile("s_waitcnt vmcnt(2)" ::: "memory");  // A(t+1)+B(t+1) landed
    } else if (t + 1 < nt) {
      asm volatile("s_waitcnt vmcnt(0)" ::: "memory");  // tail
    }
    __builtin_amdgcn_s_barrier();
    __builtin_amdgcn_sched_barrier(0);
  }
  // D frag: col = m0 + wc*128 + fj*16 + lr ; row = n0 + wn*64 + fi*16 + lg*4 + r

  if constexpr (MODE == 0) {
    const int br = m0 >> 10;
    #pragma unroll
    for (int fi = 0; fi < 4; ++fi) {
      #pragma unroll
      for (int r = 0; r < 4; ++r) {
        float best = acc[fi][0][r];
        int bj = 0;
        #pragma unroll
        for (int fj = 1; fj < 8; ++fj) {
          float v = acc[fi][fj][r];
          if (v > best) { best = v; bj = fj; }
        }
        int slot = (m0 + wc * 128 + bj * 16 + lr) & 1023;
        unsigned long long pk =
            ((unsigned long long)xform(best) << 32) | (unsigned)(0xFFFFFFFFu - (unsigned)slot);
        #pragma unroll
        for (int msk = 1; msk < 16; msk <<= 1) {
          unsigned long long o = __shfl_xor(pk, msk);
          if (o > pk) pk = o;
        }
        if (lr == 0)
          atomicMax(&rowPackAll[(size_t)br * 32768 + n0 + wn * 64 + fi * 16 + lg * 4 + r], pk);
      }
    }
    #pragma unroll
    for (int fj = 0; fj < 8; ++fj) {
      float cm = acc[0][fj][0];
      #pragma unroll
      for (int fi = 0; fi < 4; ++fi)
        #pragma unroll
        for (int r = 0; r < 4; ++r) cm = fmaxf(cm, acc[fi][fj][r]);
      cm = fmaxf(cm, __shfl_xor(cm, 16));
      cm = fmaxf(cm, __shfl_xor(cm, 32));
      if (lg == 0) atomicMax(&colMaxAll[m0 + wc * 128 + fj * 16 + lr], xform(cm));
    }
  }

  if constexpr (MODE == 1) {
    const int br = m0 >> 10;
    __syncthreads();
    unsigned short(*bt)[258] = (unsigned short(*)[258])sm;  // 128 x 256 (+pad)
    #pragma unroll
    for (int fi = 0; fi < 4; ++fi) {
      #pragma unroll
      for (int r = 0; r < 4; ++r) {
        int rowl = wn * 64 + fi * 16 + lg * 4 + r;
        float p = 0.f;
        #pragma unroll
        for (int fj = 0; fj < 8; ++fj) {
          float e = __expf(acc[fi][fj][r]);
          p += e;
          bt[rowl][wc * 128 + fj * 16 + lr] = f2bf(e);
        }
        #pragma unroll
        for (int msk = 1; msk < 16; msk <<= 1) p += __shfl_xor(p, msk);
        if (lr == 0) atomicAdd(&rowsumAll[(size_t)br * 32768 + n0 + rowl], p);
      }
    }
    __syncthreads();
    int row = tid >> 1, half = tid & 1;  // 128 rows x 2 halves of 128 cols
    unsigned short* dst = Eout + (size_t)(n0 + row) * 2048 + m0 + half * 128;
    const unsigned* su = (const unsigned*)(bt[row] + half * 128);
    #pragma unroll
    for (int i = 0; i < 16; ++i) {
      uint4 q4 = make_uint4(su[i * 4 + 0], su[i * 4 + 1], su[i * 4 + 2], su[i * 4 + 3]);
      *(uint4*)(dst + i * 8) = q4;
    }
  }

  if constexpr (MODE == 2) {
    const int br = m0 >> 9;
    const int m0l = m0 & 511;
    float(*bt32)[129] = (float(*)[129])sm;  // 128 ch x 128 px (+pad), 66 KB
    const int b = n0 >> 12, hw0 = n0 & 4095;
    const float* rsp = rowsumAll + (size_t)br * 32768;
    #pragma unroll
    for (int h2 = 0; h2 < 2; ++h2) {
      __syncthreads();
      if (wc == h2) {
        #pragma unroll
        for (int fi = 0; fi < 4; ++fi) {
          #pragma unroll
          for (int r = 0; r < 4; ++r) {
            int rowl = wn * 64 + fi * 16 + lg * 4 + r;
            float inv = 1.0f / rsp[n0 + rowl];
            #pragma unroll
            for (int fj = 0; fj < 8; ++fj)
              bt32[fj * 16 + lr][rowl] = acc[fi][fj][r] * inv;
          }
        }
      }
      __syncthreads();
      float* ob = out + ((size_t)b * 2048 + 512 + br * 1024 + m0l + h2 * 128) * 4096 + hw0;
      #pragma unroll
      for (int j = 0; j < 16; ++j) {
        int idx = j * 256 + tid;
        int ch = idx >> 5;   // 0..127
        int f4 = idx & 31;   // float4 index within 128 px
        *(float4*)&ob[(size_t)ch * 4096 + f4 * 4] = *(const float4*)&bt32[ch][f4 * 4];
      }
    }
  }
}

// ---------------- w/col unpack + slot histogram (both branches) --------------
__global__ void kwcol(const unsigned long long* __restrict__ rowPackAll,
                      const unsigned* __restrict__ colMaxAll,
                      float* __restrict__ wArr, int* __restrict__ colArr,
                      int* __restrict__ count) {
  int br = blockIdx.y;
  int n = blockIdx.x * 256 + threadIdx.x;
  unsigned long long pk = rowPackAll[(size_t)br * 32768 + n];
  float smax = inv_xform((unsigned)(pk >> 32));
  int slot = (int)(0xFFFFFFFFu - (unsigned)(pk & 0xFFFFFFFFu));
  wArr[(size_t)br * 32768 + n] = __expf(smax - inv_xform(colMaxAll[br * 1024 + slot]));
  colArr[(size_t)br * 32768 + n] = slot;
  atomicAdd(&count[br * 1024 + slot], 1);
}

// ---------------- exclusive prefix over 1024 counts (per branch) -------------
__global__ void kprefix(const int* __restrict__ count, int* __restrict__ start,
                        int* __restrict__ cursor) {
  __shared__ int sm[1024];
  int br = blockIdx.x;
  int t = threadIdx.x;
  int v = count[br * 1024 + t];
  sm[t] = v;
  __syncthreads();
  int acc = v;
  #pragma unroll
  for (int off = 1; off < 1024; off <<= 1) {
    int o = (t >= off) ? sm[t - off] : 0;
    __syncthreads();
    acc += o;
    sm[t] = acc;
    __syncthreads();
  }
  int ex = acc - v;  // exclusive prefix (branch-local)
  start[br * 1024 + t] = ex;
  cursor[br * 1024 + t] = ex;
}

// ---------------- bucket query indices by slot (both branches) ---------------
__global__ void kfill(const int* __restrict__ colArr, int* __restrict__ cursor,
                      int* __restrict__ idxArr) {
  int br = blockIdx.y;
  int n = blockIdx.x * 256 + threadIdx.x;
  int pos = atomicAdd(&cursor[br * 1024 + colArr[(size_t)br * 32768 + n]], 1);
  idxArr[(size_t)br * 32768 + pos] = n;
}

// ------- gather segment-sum + mem add + l2norm -> mu (concat) + muT (concat) -
__global__ __launch_bounds__(256) void kgathermem(
    const unsigned short* __restrict__ qf, const float* __restrict__ wArr,
    const int* __restrict__ idxArr, const int* __restrict__ start,
    const int* __restrict__ count, const float* __restrict__ memR,
    const float* __restrict__ memF,
    unsigned short* __restrict__ mu, unsigned short* __restrict__ muT) {
  __shared__ int sidx[1024];
  __shared__ float sw[1024];
  __shared__ float red[4];
  int m = blockIdx.x, br = blockIdx.y, t = threadIdx.x;
  int s = start[br * 1024 + m], cnt = count[br * 1024 + m];
  const int* idx = idxArr + (size_t)br * 32768;
  const float* w = wArr + (size_t)br * 32768;
  const float* mem = br ? memF : memR;
  float a0 = 0.f, a1 = 0.f;
  for (int base = 0; base < cnt; base += 1024) {
    int lim = min(cnt - base, 1024);
    __syncthreads();
    for (int e = t; e < lim; e += 256) {
      int n = idx[s + base + e];
      sidx[e] = n;
      sw[e] = w[n];
    }
    __syncthreads();
    for (int e = 0; e < lim; ++e) {
      int n = sidx[e];
      float wn = sw[e];
      unsigned pv = *(const unsigned*)(qf + (size_t)n * 512 + 2 * t);
      a0 += wn * bf2f((unsigned short)(pv & 0xFFFFu));
      a1 += wn * bf2f((unsigned short)(pv >> 16));
    }
  }
  float2 mv = *(const float2*)(mem + (size_t)m * 512 + 2 * t);
  a0 += mv.x;
  a1 += mv.y;
  float ss = a0 * a0 + a1 * a1;
  #pragma unroll
  for (int k = 1; k < 64; k <<= 1) ss += __shfl_xor(ss, k);
  __syncthreads();
  if ((t & 63) == 0) red[t >> 6] = ss;
  __syncthreads();
  float tot = red[0] + red[1] + red[2] + red[3];
  float rn = 1.0f / fmaxf(sqrtf(tot), 1e-12f);
  unsigned short b0 = f2bf(a0 * rn), b1 = f2bf(a1 * rn);
  *(unsigned*)(mu + ((size_t)br * 1024 + m) * 512 + 2 * t) = (unsigned)b0 | ((unsigned)b1 << 16);
  muT[(size_t)(br * 512 + 2 * t) * 1024 + m] = b0;
  muT[(size_t)(br * 512 + 2 * t + 1) * 1024 + m] = b1;
}

extern "C" void kernel_launch(void* const* d_in, const int* in_sizes, int n_in,
                              void* d_out, int out_size, void* d_ws, size_t ws_size,
                              hipStream_t stream) {
  const float* feat = (const float*)d_in[0];
  const float* memR = (const float*)d_in[2];
  const float* memF = (const float*)d_in[3];
  float* out = (float*)d_out;
  char* ws = (char*)d_ws;

  size_t off = 0;
  auto alloc = [&](size_t bytes) {
    void* p = ws + off;
    off += (bytes + 255) & ~(size_t)255;
    return p;
  };
  unsigned short* qf = (unsigned short*)alloc(33554432);    // [32768,512] bf16
  unsigned short* E = (unsigned short*)alloc(134217728);    // [32768,2048] bf16
  unsigned long long* rowPackAll = (unsigned long long*)alloc(524288);  // zero start
  unsigned* colMaxAll = (unsigned*)alloc(8192);
  float* rowsumAll = (float*)alloc(262144);
  int* count = (int*)alloc(8192);
  int* cursor = (int*)alloc(8192);                          // zero end
  size_t zero_bytes = ((char*)cursor + 8192) - (char*)rowPackAll;
  int* start = (int*)alloc(8192);
  float* wArr = (float*)alloc(262144);
  int* colArr = (int*)alloc(262144);
  int* idxArr = (int*)alloc(262144);
  unsigned short* mu = (unsigned short*)alloc(2097152);     // [2048,512] bf16
  unsigned short* muT = (unsigned short*)alloc(2097152);    // [1024,1024] bf16
  unsigned short* memB = (unsigned short*)alloc(2097152);   // [2048,512] bf16
  if (off > ws_size) return;  // workspace too small: fail validation cleanly

  // mems -> bf16 + zero-fill rowPackAll..cursor (replaces separate memset)
  kcvt2z<<<4096, 256, 0, stream>>>(memR, memF, memB, (uint4*)rowPackAll,
                                   (int)(zero_bytes >> 4));
  kqf2<<<512, 256, 0, stream>>>(feat, (unsigned*)qf, out);

  // score pass (both branches): M=2048 (8 m-tiles), N=32768 (256 n-tiles)
  gemmW<0, 3, 512><<<2048, 256, 0, stream>>>(qf, memB, 512, 512,
                                             rowPackAll, colMaxAll, nullptr, nullptr, nullptr);
  kwcol<<<dim3(128, 2), 256, 0, stream>>>(rowPackAll, colMaxAll, wArr, colArr, count);
  kprefix<<<2, 1024, 0, stream>>>(count, start, cursor);
  kfill<<<dim3(128, 2), 256, 0, stream>>>(colArr, cursor, idxArr);
  kgathermem<<<dim3(1024, 2), 256, 0, stream>>>(qf, wArr, idxArr, start, count,
                                                memR, memF, mu, muT);
  // read pass (both branches): M=2048 (8 m-tiles)
  gemmW<1, 3, 512><<<2048, 256, 0, stream>>>(qf, mu, 512, 512,
                                             nullptr, nullptr, E, rowsumAll, nullptr);
  // PV pass (both branches): M=1024 channels (4 m-tiles), K=1024
  gemmW<2, 2, 1024><<<1024, 256, 0, stream>>>(E, muT, 2048, 1024,
                                              nullptr, nullptr, nullptr, rowsumAll, out);
}

// Round 19
// 398.714 us; speedup vs baseline: 1.4686x; 1.4686x over previous
//
#include <hip/hip_runtime.h>
#include <stdint.h>

typedef __attribute__((ext_vector_type(8))) short bf16x8;
typedef __attribute__((ext_vector_type(4))) float f32x4;

__device__ __forceinline__ unsigned short f2bf(float f) {
  unsigned u = __float_as_uint(f);
  u += 0x7FFFu + ((u >> 16) & 1u);
  return (unsigned short)(u >> 16);
}
__device__ __forceinline__ float bf2f(unsigned short b) {
  return __uint_as_float(((unsigned)b) << 16);
}
// monotone float->u32 transform (order-preserving), and inverse
__device__ __forceinline__ unsigned xform(float s) {
  unsigned u = __float_as_uint(s);
  return (u & 0x80000000u) ? ~u : (u | 0x80000000u);
}
__device__ __forceinline__ float inv_xform(unsigned t) {
  unsigned u = (t & 0x80000000u) ? (t & 0x7FFFFFFFu) : ~t;
  return __uint_as_float(u);
}

__device__ __forceinline__ void gl_lds16(const void* g, void* l) {
  __builtin_amdgcn_global_load_lds(
      (const __attribute__((address_space(1))) unsigned*)g,
      (__attribute__((address_space(3))) unsigned*)l, 16, 0, 0);
}

// ---- both mems fp32 -> bf16 into concat buffer [2048,512] + zero scratch ----
__global__ void kcvt2z(const float* __restrict__ memR, const float* __restrict__ memF,
                       unsigned short* __restrict__ memB, uint4* __restrict__ zbuf,
                       int nz4) {
  int i = blockIdx.x * 256 + threadIdx.x;  // 0..1048575
  const float* src = (i < 524288) ? memR : memF;
  memB[i] = f2bf(src[i & 524287]);
  if (i < nz4) zbuf[i] = make_uint4(0u, 0u, 0u, 0u);
}

// ------- fused: per-pixel l2norm + q fp32 out (both regions) + qf bf16 -------
__global__ __launch_bounds__(256) void kqf2(const float* __restrict__ feat,
                                            unsigned* __restrict__ qf32,
                                            float* __restrict__ out) {
  __shared__ unsigned buf[32 * 256];  // 32 KiB
  __shared__ float red[4][64];
  int n0 = blockIdx.x * 64;
  int lane = threadIdx.x & 63, wv = threadIdx.x >> 6;
  int b = n0 >> 12, hw0 = n0 & 4095;
  const float* fp = feat + (size_t)b * (512 * 4096) + (size_t)(wv * 128) * 4096 + hw0 + lane;
  unsigned pk[64];
  float ss = 0.f;
  #pragma unroll
  for (int i = 0; i < 64; ++i) {
    float v0 = fp[(size_t)(2 * i) * 4096];
    float v1 = fp[(size_t)(2 * i + 1) * 4096];
    ss += v0 * v0 + v1 * v1;
    pk[i] = (unsigned)f2bf(v0) | ((unsigned)f2bf(v1) << 16);
  }
  red[wv][lane] = ss;
  __syncthreads();
  float tot = red[0][lane] + red[1][lane] + red[2][lane] + red[3][lane];
  float rn = 1.0f / fmaxf(sqrtf(tot), 1e-12f);
  float* ob = out + ((size_t)b * 2048 + wv * 128) * 4096 + hw0 + lane;
  #pragma unroll
  for (int i = 0; i < 64; ++i) {
    float q0 = bf2f((unsigned short)(pk[i] & 0xFFFFu)) * rn;
    float q1 = bf2f((unsigned short)(pk[i] >> 16)) * rn;
    ob[(size_t)(2 * i) * 4096] = q0;
    ob[(size_t)(2 * i) * 4096 + (size_t)1024 * 4096] = q0;
    ob[(size_t)(2 * i + 1) * 4096] = q1;
    ob[(size_t)(2 * i + 1) * 4096 + (size_t)1024 * 4096] = q1;
    pk[i] = (unsigned)f2bf(q0) | ((unsigned)f2bf(q1) << 16);
  }
  #pragma unroll
  for (int p = 0; p < 2; ++p) {
    __syncthreads();
    if ((lane >> 5) == p) {
      int px = lane & 31;
      #pragma unroll
      for (int i = 0; i < 64; ++i) buf[px * 256 + ((wv * 64 + i) ^ px)] = pk[i];
    }
    __syncthreads();
    #pragma unroll
    for (int r = 0; r < 32; ++r) {
      int row = p * 32 + r;
      qf32[(size_t)(n0 + row) * 256 + threadIdx.x] = buf[r * 256 + (threadIdx.x ^ r)];
    }
  }
}

// ---- merged GEMM (A[*,K] x B[*,K]^T), 128n x 256m tile, BK=32, ring-3 -------
// 4 waves (wn = wid>>1, wc = wid&1); per-wave 64n x 128m output: acc[4][8],
// 12 ds_read_b128 per 32 MFMA -> LDS (~1130cy) vs MFMA (~1030cy) balanced.
// Ring: 3 slots x 24 KB (A 128x32 + B 256x32) = 72 KB -> 2 blocks/CU.
// iter t: ds_read(slot t%3); issue STAGE((t+2)%3) [6 loads/thread]; 32 MFMA;
//         vmcnt(6) [t+1 landed, t+2 in flight]; barrier.  Never vmcnt(0) mid-loop.
// Double-XOR swizzle (lane-constant both sides) keeps staging + ds_read free.
// MODE 0: score pass  -> rowPackAll (u64 max) + colMaxAll (u32 max); br = m0>>10
// MODE 1: read pass   -> E[n, 2048] = exp(score2) bf16 + rowsumAll atomics
// MODE 2: PV pass     -> out = (E_br @ muT)/rowsum, fp32 transposed store; br = m0>>9
template <int MODE, int LGX, int K>
__global__ __launch_bounds__(256, 2) void gemmW(
    const unsigned short* __restrict__ A, const unsigned short* __restrict__ B,
    int lda, int ldb,
    unsigned long long* __restrict__ rowPackAll, unsigned* __restrict__ colMaxAll,
    unsigned short* __restrict__ Eout, float* __restrict__ rowsumAll,
    float* __restrict__ out) {
  __shared__ __align__(16) unsigned short sm[36864];  // 73728 B: 3 ring slots
  const int bid = blockIdx.x;
  const int xcd = bid & 7;
  const int tt0 = bid >> 3;
  const int m0 = (tt0 & ((1 << LGX) - 1)) * 256;
  const int n0 = (xcd + (tt0 >> LGX) * 8) * 128;
  const int tid = threadIdx.x;
  const int wid = tid >> 6, lane = tid & 63;
  const int wn = wid >> 1, wc = wid & 1;
  const int lr = lane & 15, lg = lane >> 4;
  // staging source chunk pre-swizzle (lane-constant):
  const int ssw = ((tid & 3) ^ ((tid >> 2) & 3) ^ ((tid >> 4) & 3)) * 8;
  // read-side swizzle (lane-constant, fragment-row-independent):
  const int rsw = (lg ^ (lr & 3) ^ ((lr >> 2) & 3)) * 8;
  const size_t brOffA = (MODE == 2) ? (size_t)((m0 >> 9) * 1024) : 0;
  constexpr int nt = K >> 5;

  f32x4 acc[4][8];
  #pragma unroll
  for (int i = 0; i < 4; ++i)
    #pragma unroll
    for (int j = 0; j < 8; ++j) acc[i][j] = (f32x4){0.f, 0.f, 0.f, 0.f};

  auto STAGE = [&](int slot, int t) {
    const int k0 = t << 5;
    #pragma unroll
    for (int i = 0; i < 2; ++i) {
      int row = i * 64 + (tid >> 2);
      gl_lds16(A + brOffA + (size_t)(n0 + row) * lda + k0 + ssw,
               sm + slot * 12288 + i * 2048 + wid * 512);
    }
    #pragma unroll
    for (int i = 0; i < 4; ++i) {
      int row = i * 64 + (tid >> 2);
      gl_lds16(B + (size_t)(m0 + row) * ldb + k0 + ssw,
               sm + slot * 12288 + 4096 + i * 2048 + wid * 512);
    }
  };

  // prologue: K-steps 0,1 staged; wait step 0 (step 1's 6 loads stay in flight)
  STAGE(0, 0);
  STAGE(1, 1);
  asm volatile("s_waitcnt vmcnt(6)" ::: "memory");
  __builtin_amdgcn_s_barrier();
  __builtin_amdgcn_sched_barrier(0);

  #pragma unroll
  for (int t = 0; t < nt; ++t) {
    const int slot = t % 3;
    const unsigned short* As = sm + slot * 12288;
    const unsigned short* Bs = As + 4096;
    bf16x8 af[4], bfr[8];
    #pragma unroll
    for (int f = 0; f < 4; ++f)
      af[f] = *(const bf16x8*)&As[(wn * 64 + f * 16 + lr) * 32 + rsw];
    #pragma unroll
    for (int f = 0; f < 8; ++f)
      bfr[f] = *(const bf16x8*)&Bs[(wc * 128 + f * 16 + lr) * 32 + rsw];
    if (t + 2 < nt) STAGE((t + 2) % 3, t + 2);  // refill slot freed at t-1
    __builtin_amdgcn_s_setprio(1);
    #pragma unroll
    for (int fi = 0; fi < 4; ++fi)
      #pragma unroll
      for (int fj = 0; fj < 8; ++fj)
        acc[fi][fj] = __builtin_amdgcn_mfma_f32_16x16x32_bf16(af[fi], bfr[fj], acc[fi][fj], 0, 0, 0);
    __builtin_amdgcn_s_setprio(0);
    if (t + 2 < nt) {
      asm volatile("s_waitcnt vmcnt(6)" ::: "memory");   // t+1 landed; t+2 in flight
    } else if (t + 1 < nt) {
      asm volatile("s_waitcnt vmcnt(0)" ::: "memory");   // tail
    }
    __builtin_amdgcn_s_barrier();
    __builtin_amdgcn_sched_barrier(0);
  }
  // D frag: col = m0 + wc*128 + fj*16 + lr ; row = n0 + wn*64 + fi*16 + lg*4 + r

  if constexpr (MODE == 0) {
    const int br = m0 >> 10;
    #pragma unroll
    for (int fi = 0; fi < 4; ++fi) {
      #pragma unroll
      for (int r = 0; r < 4; ++r) {
        float best = acc[fi][0][r];
        int bj = 0;
        #pragma unroll
        for (int fj = 1; fj < 8; ++fj) {
          float v = acc[fi][fj][r];
          if (v > best) { best = v; bj = fj; }
        }
        int slot = (m0 + wc * 128 + bj * 16 + lr) & 1023;
        unsigned long long pk =
            ((unsigned long long)xform(best) << 32) | (unsigned)(0xFFFFFFFFu - (unsigned)slot);
        #pragma unroll
        for (int msk = 1; msk < 16; msk <<= 1) {
          unsigned long long o = __shfl_xor(pk, msk);
          if (o > pk) pk = o;
        }
        if (lr == 0)
          atomicMax(&rowPackAll[(size_t)br * 32768 + n0 + wn * 64 + fi * 16 + lg * 4 + r], pk);
      }
    }
    #pragma unroll
    for (int fj = 0; fj < 8; ++fj) {
      float cm = acc[0][fj][0];
      #pragma unroll
      for (int fi = 0; fi < 4; ++fi)
        #pragma unroll
        for (int r = 0; r < 4; ++r) cm = fmaxf(cm, acc[fi][fj][r]);
      cm = fmaxf(cm, __shfl_xor(cm, 16));
      cm = fmaxf(cm, __shfl_xor(cm, 32));
      if (lg == 0) atomicMax(&colMaxAll[m0 + wc * 128 + fj * 16 + lr], xform(cm));
    }
  }

  if constexpr (MODE == 1) {
    const int br = m0 >> 10;
    __syncthreads();
    unsigned short(*bt)[258] = (unsigned short(*)[258])sm;  // 128 x 256 (+pad)
    #pragma unroll
    for (int fi = 0; fi < 4; ++fi) {
      #pragma unroll
      for (int r = 0; r < 4; ++r) {
        int rowl = wn * 64 + fi * 16 + lg * 4 + r;
        float p = 0.f;
        #pragma unroll
        for (int fj = 0; fj < 8; ++fj) {
          float e = __expf(acc[fi][fj][r]);
          p += e;
          bt[rowl][wc * 128 + fj * 16 + lr] = f2bf(e);
        }
        #pragma unroll
        for (int msk = 1; msk < 16; msk <<= 1) p += __shfl_xor(p, msk);
        if (lr == 0) atomicAdd(&rowsumAll[(size_t)br * 32768 + n0 + rowl], p);
      }
    }
    __syncthreads();
    int row = tid >> 1, half = tid & 1;  // 128 rows x 2 halves of 128 cols
    unsigned short* dst = Eout + (size_t)(n0 + row) * 2048 + m0 + half * 128;
    const unsigned* su = (const unsigned*)(bt[row] + half * 128);
    #pragma unroll
    for (int i = 0; i < 16; ++i) {
      uint4 q4 = make_uint4(su[i * 4 + 0], su[i * 4 + 1], su[i * 4 + 2], su[i * 4 + 3]);
      *(uint4*)(dst + i * 8) = q4;
    }
  }

  if constexpr (MODE == 2) {
    const int br = m0 >> 9;
    const int m0l = m0 & 511;
    float(*bt32)[129] = (float(*)[129])sm;  // 128 ch x 128 px (+pad), 66 KB
    const int b = n0 >> 12, hw0 = n0 & 4095;
    const float* rsp = rowsumAll + (size_t)br * 32768;
    #pragma unroll
    for (int h2 = 0; h2 < 2; ++h2) {
      __syncthreads();
      if (wc == h2) {
        #pragma unroll
        for (int fi = 0; fi < 4; ++fi) {
          #pragma unroll
          for (int r = 0; r < 4; ++r) {
            int rowl = wn * 64 + fi * 16 + lg * 4 + r;
            float inv = 1.0f / rsp[n0 + rowl];
            #pragma unroll
            for (int fj = 0; fj < 8; ++fj)
              bt32[fj * 16 + lr][rowl] = acc[fi][fj][r] * inv;
          }
        }
      }
      __syncthreads();
      float* ob = out + ((size_t)b * 2048 + 512 + br * 1024 + m0l + h2 * 128) * 4096 + hw0;
      #pragma unroll
      for (int j = 0; j < 16; ++j) {
        int idx = j * 256 + tid;
        int ch = idx >> 5;   // 0..127
        int f4 = idx & 31;   // float4 index within 128 px
        *(float4*)&ob[(size_t)ch * 4096 + f4 * 4] = *(const float4*)&bt32[ch][f4 * 4];
      }
    }
  }
}

// ---------------- w/col unpack + slot histogram (both branches) --------------
__global__ void kwcol(const unsigned long long* __restrict__ rowPackAll,
                      const unsigned* __restrict__ colMaxAll,
                      float* __restrict__ wArr, int* __restrict__ colArr,
                      int* __restrict__ count) {
  int br = blockIdx.y;
  int n = blockIdx.x * 256 + threadIdx.x;
  unsigned long long pk = rowPackAll[(size_t)br * 32768 + n];
  float smax = inv_xform((unsigned)(pk >> 32));
  int slot = (int)(0xFFFFFFFFu - (unsigned)(pk & 0xFFFFFFFFu));
  wArr[(size_t)br * 32768 + n] = __expf(smax - inv_xform(colMaxAll[br * 1024 + slot]));
  colArr[(size_t)br * 32768 + n] = slot;
  atomicAdd(&count[br * 1024 + slot], 1);
}

// ---------------- exclusive prefix over 1024 counts (per branch) -------------
__global__ void kprefix(const int* __restrict__ count, int* __restrict__ start,
                        int* __restrict__ cursor) {
  __shared__ int sm[1024];
  int br = blockIdx.x;
  int t = threadIdx.x;
  int v = count[br * 1024 + t];
  sm[t] = v;
  __syncthreads();
  int acc = v;
  #pragma unroll
  for (int off = 1; off < 1024; off <<= 1) {
    int o = (t >= off) ? sm[t - off] : 0;
    __syncthreads();
    acc += o;
    sm[t] = acc;
    __syncthreads();
  }
  int ex = acc - v;  // exclusive prefix (branch-local)
  start[br * 1024 + t] = ex;
  cursor[br * 1024 + t] = ex;
}

// ---------------- bucket query indices by slot (both branches) ---------------
__global__ void kfill(const int* __restrict__ colArr, int* __restrict__ cursor,
                      int* __restrict__ idxArr) {
  int br = blockIdx.y;
  int n = blockIdx.x * 256 + threadIdx.x;
  int pos = atomicAdd(&cursor[br * 1024 + colArr[(size_t)br * 32768 + n]], 1);
  idxArr[(size_t)br * 32768 + pos] = n;
}

// ------- gather segment-sum + mem add + l2norm -> mu (concat) + muT (concat) -
__global__ __launch_bounds__(256) void kgathermem(
    const unsigned short* __restrict__ qf, const float* __restrict__ wArr,
    const int* __restrict__ idxArr, const int* __restrict__ start,
    const int* __restrict__ count, const float* __restrict__ memR,
    const float* __restrict__ memF,
    unsigned short* __restrict__ mu, unsigned short* __restrict__ muT) {
  __shared__ int sidx[1024];
  __shared__ float sw[1024];
  __shared__ float red[4];
  int m = blockIdx.x, br = blockIdx.y, t = threadIdx.x;
  int s = start[br * 1024 + m], cnt = count[br * 1024 + m];
  const int* idx = idxArr + (size_t)br * 32768;
  const float* w = wArr + (size_t)br * 32768;
  const float* mem = br ? memF : memR;
  float a0 = 0.f, a1 = 0.f;
  for (int base = 0; base < cnt; base += 1024) {
    int lim = min(cnt - base, 1024);
    __syncthreads();
    for (int e = t; e < lim; e += 256) {
      int n = idx[s + base + e];
      sidx[e] = n;
      sw[e] = w[n];
    }
    __syncthreads();
    for (int e = 0; e < lim; ++e) {
      int n = sidx[e];
      float wn = sw[e];
      unsigned pv = *(const unsigned*)(qf + (size_t)n * 512 + 2 * t);
      a0 += wn * bf2f((unsigned short)(pv & 0xFFFFu));
      a1 += wn * bf2f((unsigned short)(pv >> 16));
    }
  }
  float2 mv = *(const float2*)(mem + (size_t)m * 512 + 2 * t);
  a0 += mv.x;
  a1 += mv.y;
  float ss = a0 * a0 + a1 * a1;
  #pragma unroll
  for (int k = 1; k < 64; k <<= 1) ss += __shfl_xor(ss, k);
  __syncthreads();
  if ((t & 63) == 0) red[t >> 6] = ss;
  __syncthreads();
  float tot = red[0] + red[1] + red[2] + red[3];
  float rn = 1.0f / fmaxf(sqrtf(tot), 1e-12f);
  unsigned short b0 = f2bf(a0 * rn), b1 = f2bf(a1 * rn);
  *(unsigned*)(mu + ((size_t)br * 1024 + m) * 512 + 2 * t) = (unsigned)b0 | ((unsigned)b1 << 16);
  muT[(size_t)(br * 512 + 2 * t) * 1024 + m] = b0;
  muT[(size_t)(br * 512 + 2 * t + 1) * 1024 + m] = b1;
}

extern "C" void kernel_launch(void* const* d_in, const int* in_sizes, int n_in,
                              void* d_out, int out_size, void* d_ws, size_t ws_size,
                              hipStream_t stream) {
  const float* feat = (const float*)d_in[0];
  const float* memR = (const float*)d_in[2];
  const float* memF = (const float*)d_in[3];
  float* out = (float*)d_out;
  char* ws = (char*)d_ws;

  size_t off = 0;
  auto alloc = [&](size_t bytes) {
    void* p = ws + off;
    off += (bytes + 255) & ~(size_t)255;
    return p;
  };
  unsigned short* qf = (unsigned short*)alloc(33554432);    // [32768,512] bf16
  unsigned short* E = (unsigned short*)alloc(134217728);    // [32768,2048] bf16
  unsigned long long* rowPackAll = (unsigned long long*)alloc(524288);  // zero start
  unsigned* colMaxAll = (unsigned*)alloc(8192);
  float* rowsumAll = (float*)alloc(262144);
  int* count = (int*)alloc(8192);
  int* cursor = (int*)alloc(8192);                          // zero end
  size_t zero_bytes = ((char*)cursor + 8192) - (char*)rowPackAll;
  int* start = (int*)alloc(8192);
  float* wArr = (float*)alloc(262144);
  int* colArr = (int*)alloc(262144);
  int* idxArr = (int*)alloc(262144);
  unsigned short* mu = (unsigned short*)alloc(2097152);     // [2048,512] bf16
  unsigned short* muT = (unsigned short*)alloc(2097152);    // [1024,1024] bf16
  unsigned short* memB = (unsigned short*)alloc(2097152);   // [2048,512] bf16
  if (off > ws_size) return;  // workspace too small: fail validation cleanly

  // mems -> bf16 + zero-fill rowPackAll..cursor (replaces separate memset)
  kcvt2z<<<4096, 256, 0, stream>>>(memR, memF, memB, (uint4*)rowPackAll,
                                   (int)(zero_bytes >> 4));
  kqf2<<<512, 256, 0, stream>>>(feat, (unsigned*)qf, out);

  // score pass (both branches): M=2048 (8 m-tiles), N=32768 (256 n-tiles)
  gemmW<0, 3, 512><<<2048, 256, 0, stream>>>(qf, memB, 512, 512,
                                             rowPackAll, colMaxAll, nullptr, nullptr, nullptr);
  kwcol<<<dim3(128, 2), 256, 0, stream>>>(rowPackAll, colMaxAll, wArr, colArr, count);
  kprefix<<<2, 1024, 0, stream>>>(count, start, cursor);
  kfill<<<dim3(128, 2), 256, 0, stream>>>(colArr, cursor, idxArr);
  kgathermem<<<dim3(1024, 2), 256, 0, stream>>>(qf, wArr, idxArr, start, count,
                                                memR, memF, mu, muT);
  // read pass (both branches): M=2048 (8 m-tiles)
  gemmW<1, 3, 512><<<2048, 256, 0, stream>>>(qf, mu, 512, 512,
                                             nullptr, nullptr, E, rowsumAll, nullptr);
  // PV pass (both branches): M=1024 channels (4 m-tiles), K=1024
  gemmW<2, 2, 1024><<<1024, 256, 0, stream>>>(E, muT, 2048, 1024,
                                              nullptr, nullptr, nullptr, rowsumAll, out);
}